// Round 1
// baseline (585.783 us; speedup 1.0000x reference)
//
#include <hip/hip_runtime.h>
#include <hip/hip_bf16.h>

#define S 2048
#define HID 4096
#define NH 32
#define NKV 8
#define HD 128
#define QKVN 6144  // NH*HD + 2*NKV*HD

typedef __attribute__((ext_vector_type(8))) short bf16x8;
typedef __attribute__((ext_vector_type(4))) float f32x4;
typedef __attribute__((ext_vector_type(8))) unsigned short u16x8;

__device__ __forceinline__ unsigned short f2bf(float f) {
  union { float f; unsigned u; } c; c.f = f;
  unsigned u = c.u;
  return (unsigned short)((u + 0x7FFFu + ((u >> 16) & 1u)) >> 16);
}
__device__ __forceinline__ float bf2f(unsigned short h) {
  union { unsigned u; float f; } c; c.u = ((unsigned)h) << 16;
  return c.f;
}

// ---------------- fp32 -> bf16 convert (vector4) ----------------
__global__ void convert_kernel(const float* __restrict__ in,
                               unsigned short* __restrict__ out, int n4) {
  int i = blockIdx.x * blockDim.x + threadIdx.x;
  if (i < n4) {
    float4 v = ((const float4*)in)[i];
    ushort4 o;
    o.x = f2bf(v.x); o.y = f2bf(v.y); o.z = f2bf(v.z); o.w = f2bf(v.w);
    ((ushort4*)out)[i] = o;
  }
}

// ---------------- transpose + convert: in [K][N] f32 -> out [N][K=4096] bf16 ----------------
__global__ void transpose_convert(const float* __restrict__ in,
                                  unsigned short* __restrict__ out, int N) {
  __shared__ float tile[32][33];
  int tx = threadIdx.x, ty = threadIdx.y;       // 32 x 8
  int n0 = blockIdx.x * 32, k0 = blockIdx.y * 32;
#pragma unroll
  for (int i = 0; i < 32; i += 8)
    tile[ty + i][tx] = in[(size_t)(k0 + ty + i) * N + n0 + tx];
  __syncthreads();
#pragma unroll
  for (int i = 0; i < 32; i += 8)
    out[(size_t)(n0 + ty + i) * HID + k0 + tx] = f2bf(tile[tx][ty + i]);
}

// ---------------- bf16 GEMM: C[M][N] = A[M][K] * Bt[N][K]^T ----------------
// 128x128 tile, BK=32, 256 threads (4 waves as 2x2, each wave 64x64)
__device__ __forceinline__ void storeC(unsigned short* C, size_t idx, float v) { C[idx] = f2bf(v); }
__device__ __forceinline__ void storeC(float* C, size_t idx, float v) { C[idx] = v; }

template <typename OutT>
__launch_bounds__(256)
__global__ void gemm_bt(const unsigned short* __restrict__ A,
                        const unsigned short* __restrict__ Bt,
                        OutT* __restrict__ C, int K, int ldc) {
  __shared__ unsigned short As[128 * 40];  // padded stride 40 (2-way max conflict)
  __shared__ unsigned short Bs[128 * 40];
  int tid = threadIdx.x, lane = tid & 63, w = tid >> 6;
  int wr = w >> 1, wc = w & 1;
  int m0 = blockIdx.y * 128, n0 = blockIdx.x * 128;
  int lrow = lane & 15, lk = (lane >> 4) << 3;

  f32x4 acc[4][4];
  f32x4 zero = {0.f, 0.f, 0.f, 0.f};
#pragma unroll
  for (int mi = 0; mi < 4; ++mi)
#pragma unroll
    for (int ni = 0; ni < 4; ++ni) acc[mi][ni] = zero;

  int ar = tid >> 1, ac = (tid & 1) << 4;  // each thread stages 16 elems of A and B
  const unsigned short* Ag = A + (size_t)(m0 + ar) * K + ac;
  const unsigned short* Bg = Bt + (size_t)(n0 + ar) * K + ac;

  for (int kt = 0; kt < K; kt += 32) {
    *(u16x8*)&As[ar * 40 + ac]     = *(const u16x8*)(Ag + kt);
    *(u16x8*)&As[ar * 40 + ac + 8] = *(const u16x8*)(Ag + kt + 8);
    *(u16x8*)&Bs[ar * 40 + ac]     = *(const u16x8*)(Bg + kt);
    *(u16x8*)&Bs[ar * 40 + ac + 8] = *(const u16x8*)(Bg + kt + 8);
    __syncthreads();
    bf16x8 af[4], bfr[4];
#pragma unroll
    for (int mi = 0; mi < 4; ++mi)
      af[mi] = *(const bf16x8*)&As[(wr * 64 + mi * 16 + lrow) * 40 + lk];
#pragma unroll
    for (int ni = 0; ni < 4; ++ni)
      bfr[ni] = *(const bf16x8*)&Bs[(wc * 64 + ni * 16 + lrow) * 40 + lk];
#pragma unroll
    for (int mi = 0; mi < 4; ++mi)
#pragma unroll
      for (int ni = 0; ni < 4; ++ni)
        acc[mi][ni] = __builtin_amdgcn_mfma_f32_16x16x32_bf16(af[mi], bfr[ni], acc[mi][ni], 0, 0, 0);
    __syncthreads();
  }

#pragma unroll
  for (int mi = 0; mi < 4; ++mi) {
#pragma unroll
    for (int ni = 0; ni < 4; ++ni) {
      int row = m0 + wr * 64 + mi * 16 + ((lane >> 4) << 2);
      int col = n0 + wc * 64 + ni * 16 + lrow;
#pragma unroll
      for (int r = 0; r < 4; ++r)
        storeC(C, (size_t)(row + r) * ldc + col, acc[mi][ni][r]);
    }
  }
}

// ---------------- RoPE (in-place on QKV buffer), scale folded into Q ----------------
__global__ void rope_kernel(unsigned short* __restrict__ qkv) {
  int idx = blockIdx.x * blockDim.x + threadIdx.x;  // S * 40 heads * 64 pairs
  int d = idx & 63;
  int h = (idx >> 6) % (NH + NKV);
  int s = (idx >> 6) / (NH + NKV);
  size_t base = (size_t)s * QKVN + (h < NH ? h * HD : NH * HD + (h - NH) * HD);
  float invf = __expf(-(float)d * (1.0f / 64.0f) * 9.210340371976184f);  // 10000^(-d/64)
  float ang = (float)s * invf;
  float c, sn;
  __sincosf(ang, &sn, &c);
  float x1 = bf2f(qkv[base + d]);
  float x2 = bf2f(qkv[base + d + 64]);
  float o1 = x1 * c - x2 * sn;
  float o2 = x2 * c + x1 * sn;
  if (h < NH) {  // fold 1/sqrt(128) attention scale into Q
    o1 *= 0.08838834764831845f;
    o2 *= 0.08838834764831845f;
  }
  qkv[base + d] = f2bf(o1);
  qkv[base + d + 64] = f2bf(o2);
}

// ---------------- flash attention: grid (qblk=32, head=32), 256 threads = 4 waves ----------------
// each wave owns 16 q-rows; KV tile = 32 rows
__launch_bounds__(256)
__global__ void attn_kernel(const unsigned short* __restrict__ qkv,
                            unsigned short* __restrict__ ao) {
  __shared__ unsigned short Ks[32 * 136];   // K tile [kv][d], stride 136
  __shared__ unsigned short Vt[128 * 40];   // V^T tile [d][kv], stride 40
  __shared__ unsigned short Ps[4][16 * 40]; // per-wave P, stride 40

  int tid = threadIdx.x, lane = tid & 63, w = tid >> 6;
  int qblk = blockIdx.x, h = blockIdx.y;
  int kh = h >> 2;  // GQA group of 4
  int lrow = lane & 15, lk16 = lane >> 4, lk = lk16 << 3;
  int qbase = qblk * 64 + w * 16;

  // preload Q fragments (d = t*32 + lk + j)
  bf16x8 qf[4];
  const unsigned short* qptr = qkv + (size_t)(qbase + lrow) * QKVN + h * HD;
#pragma unroll
  for (int t = 0; t < 4; ++t) qf[t] = *(const bf16x8*)(qptr + t * 32 + lk);

  f32x4 o[8];
  f32x4 zero = {0.f, 0.f, 0.f, 0.f};
#pragma unroll
  for (int ni = 0; ni < 8; ++ni) o[ni] = zero;
  float m[4] = {-1e30f, -1e30f, -1e30f, -1e30f};
  float l[4] = {0.f, 0.f, 0.f, 0.f};

  int kvend = qblk * 64 + 63;
  for (int kv0 = 0; kv0 <= kvend; kv0 += 32) {
    __syncthreads();  // protect prior-iteration LDS reads
    {
      // stage K tile: [32][128]
      int r = tid >> 3, c = (tid & 7) << 4;
      const unsigned short* kg = qkv + (size_t)(kv0 + r) * QKVN + NH * HD + kh * HD + c;
      *(u16x8*)&Ks[r * 136 + c]     = *(const u16x8*)kg;
      *(u16x8*)&Ks[r * 136 + c + 8] = *(const u16x8*)(kg + 8);
      // stage V transposed: Vt[d][kv]
      int r2 = tid & 31, c2 = (tid >> 5) << 4;
      const unsigned short* vg = qkv + (size_t)(kv0 + r2) * QKVN + (NH + NKV) * HD + kh * HD + c2;
      u16x8 v0 = *(const u16x8*)vg;
      u16x8 v1 = *(const u16x8*)(vg + 8);
#pragma unroll
      for (int j = 0; j < 8; ++j) Vt[(c2 + j) * 40 + r2] = v0[j];
#pragma unroll
      for (int j = 0; j < 8; ++j) Vt[(c2 + 8 + j) * 40 + r2] = v1[j];
    }
    __syncthreads();

    if (kv0 <= qbase + 15) {  // this wave still has unmasked work
      // S = Q K^T (scale already in Q)
      f32x4 sc[2];
      sc[0] = zero; sc[1] = zero;
#pragma unroll
      for (int t = 0; t < 4; ++t) {
        bf16x8 kf0 = *(const bf16x8*)&Ks[(lrow) * 136 + t * 32 + lk];
        bf16x8 kf1 = *(const bf16x8*)&Ks[(16 + lrow) * 136 + t * 32 + lk];
        sc[0] = __builtin_amdgcn_mfma_f32_16x16x32_bf16(qf[t], kf0, sc[0], 0, 0, 0);
        sc[1] = __builtin_amdgcn_mfma_f32_16x16x32_bf16(qf[t], kf1, sc[1], 0, 0, 0);
      }
      // causal mask
      int qlo = qbase + (lk16 << 2);
#pragma unroll
      for (int kb = 0; kb < 2; ++kb) {
        int kv = kv0 + kb * 16 + lrow;
#pragma unroll
        for (int r = 0; r < 4; ++r)
          if (kv > qlo + r) sc[kb][r] = -1e30f;
      }
      // online softmax
      float mn[4], rs[4], alpha[4];
#pragma unroll
      for (int r = 0; r < 4; ++r) mn[r] = fmaxf(sc[0][r], sc[1][r]);
#pragma unroll
      for (int off = 1; off < 16; off <<= 1)
#pragma unroll
        for (int r = 0; r < 4; ++r) mn[r] = fmaxf(mn[r], __shfl_xor(mn[r], off, 64));
#pragma unroll
      for (int r = 0; r < 4; ++r) {
        float mi2 = fmaxf(m[r], mn[r]);
        alpha[r] = __expf(m[r] - mi2);
        m[r] = mi2;
        float p0 = __expf(sc[0][r] - mi2);
        float p1 = __expf(sc[1][r] - mi2);
        sc[0][r] = p0; sc[1][r] = p1;
        rs[r] = p0 + p1;
      }
#pragma unroll
      for (int off = 1; off < 16; off <<= 1)
#pragma unroll
        for (int r = 0; r < 4; ++r) rs[r] += __shfl_xor(rs[r], off, 64);
#pragma unroll
      for (int r = 0; r < 4; ++r) l[r] = l[r] * alpha[r] + rs[r];
      // rescale O
#pragma unroll
      for (int ni = 0; ni < 8; ++ni)
#pragma unroll
        for (int r = 0; r < 4; ++r) o[ni][r] *= alpha[r];
      // P -> LDS (bf16), then A-fragment layout read
      unsigned short* Psw = &Ps[w][0];
#pragma unroll
      for (int kb = 0; kb < 2; ++kb)
#pragma unroll
        for (int r = 0; r < 4; ++r)
          Psw[((lk16 << 2) + r) * 40 + kb * 16 + lrow] = f2bf(sc[kb][r]);
      bf16x8 pf = *(const bf16x8*)&Psw[lrow * 40 + lk];
      // O += P V
#pragma unroll
      for (int ni = 0; ni < 8; ++ni) {
        bf16x8 vf = *(const bf16x8*)&Vt[(ni * 16 + lrow) * 40 + lk];
        o[ni] = __builtin_amdgcn_mfma_f32_16x16x32_bf16(pf, vf, o[ni], 0, 0, 0);
      }
    }
  }

  // epilogue: O / l -> ao (bf16, head-interleaved [s][NH*HD])
  float inv[4];
#pragma unroll
  for (int r = 0; r < 4; ++r) inv[r] = 1.0f / l[r];
#pragma unroll
  for (int ni = 0; ni < 8; ++ni) {
#pragma unroll
    for (int r = 0; r < 4; ++r) {
      size_t row = (size_t)(qbase + (lk16 << 2) + r);
      ao[row * (NH * HD) + h * HD + ni * 16 + lrow] = f2bf(o[ni][r] * inv[r]);
    }
  }
}

extern "C" void kernel_launch(void* const* d_in, const int* in_sizes, int n_in,
                              void* d_out, int out_size, void* d_ws, size_t ws_size,
                              hipStream_t stream) {
  const float* X  = (const float*)d_in[0];
  const float* qw = (const float*)d_in[2];
  const float* kw = (const float*)d_in[3];
  const float* vw = (const float*)d_in[4];
  const float* ow = (const float*)d_in[5];
  float* out = (float*)d_out;

  char* ws = (char*)d_ws;
  // layout: Xb [0,16M) | Wt [16M,64M) | QKV [64M,88M) | AO [88M,104M)
  // OWt reuses [0,32M) after GEMM1 (Xb and Wt-head are dead by then)
  unsigned short* Xb  = (unsigned short*)(ws);
  unsigned short* Wt  = (unsigned short*)(ws + (size_t)(16u << 20));
  unsigned short* QKV = (unsigned short*)(ws + (size_t)(64u << 20));
  unsigned short* AO  = (unsigned short*)(ws + (size_t)(88u << 20));
  unsigned short* OWt = (unsigned short*)(ws);

  dim3 tb(32, 8);

  // 1. X -> bf16
  convert_kernel<<<(S * HID / 4 + 255) / 256, 256, 0, stream>>>(X, Xb, S * HID / 4);
  // 2. weights -> bf16 transposed [N][K], q/k/v packed into Wt rows [0,6144)
  transpose_convert<<<dim3(HID / 32, HID / 32), tb, 0, stream>>>(qw, Wt, HID);
  transpose_convert<<<dim3((NKV * HD) / 32, HID / 32), tb, 0, stream>>>(kw, Wt + (size_t)(NH * HD) * HID, NKV * HD);
  transpose_convert<<<dim3((NKV * HD) / 32, HID / 32), tb, 0, stream>>>(vw, Wt + (size_t)(NH + NKV) * HD * HID, NKV * HD);
  // 3. QKV = Xb @ Wt^T  (one fused GEMM, N=6144)
  gemm_bt<unsigned short><<<dim3(QKVN / 128, S / 128), 256, 0, stream>>>(Xb, Wt, QKV, HID, QKVN);
  // 4. o_w -> bf16 transposed (into reused region; only after GEMM1 in stream order)
  transpose_convert<<<dim3(HID / 32, HID / 32), tb, 0, stream>>>(ow, OWt, HID);
  // 5. RoPE on Q and K (in place), attention scale folded into Q
  rope_kernel<<<(S * (NH + NKV) * 64) / 256, 256, 0, stream>>>(QKV);
  // 6. flash attention
  attn_kernel<<<dim3(S / 64, NH), 256, 0, stream>>>(QKV, AO);
  // 7. out = AO @ OWt^T (fp32 output)
  gemm_bt<float><<<dim3(HID / 128, S / 128), 256, 0, stream>>>(AO, OWt, out, HID, HID);
}

// Round 3
// 471.253 us; speedup vs baseline: 1.2430x; 1.2430x over previous
//
#include <hip/hip_runtime.h>
#include <hip/hip_bf16.h>

#define S 2048
#define HID 4096
#define NH 32
#define NKV 8
#define HD 128
#define QKVN 6144  // NH*HD + 2*NKV*HD

typedef __attribute__((ext_vector_type(8))) short bf16x8;
typedef __attribute__((ext_vector_type(4))) float f32x4;
typedef __attribute__((ext_vector_type(8))) unsigned short u16x8;
typedef __attribute__((ext_vector_type(4))) unsigned short u16x4;

#define GLOAD16(src, dst)                                                        \
  __builtin_amdgcn_global_load_lds(                                              \
      (const __attribute__((address_space(1))) unsigned int*)(src),              \
      (__attribute__((address_space(3))) unsigned int*)(dst), 16, 0, 0)

__device__ __forceinline__ unsigned short f2bf(float f) {
  union { float f; unsigned u; } c; c.f = f;
  unsigned u = c.u;
  return (unsigned short)((u + 0x7FFFu + ((u >> 16) & 1u)) >> 16);
}
__device__ __forceinline__ float bf2f(unsigned short h) {
  union { unsigned u; float f; } c; c.u = ((unsigned)h) << 16;
  return c.f;
}

// ---------------- fp32 -> bf16 convert (vector4) ----------------
__global__ void convert_kernel(const float* __restrict__ in,
                               unsigned short* __restrict__ out, int n4) {
  int i = blockIdx.x * blockDim.x + threadIdx.x;
  if (i < n4) {
    float4 v = ((const float4*)in)[i];
    ushort4 o;
    o.x = f2bf(v.x); o.y = f2bf(v.y); o.z = f2bf(v.z); o.w = f2bf(v.w);
    ((ushort4*)out)[i] = o;
  }
}

// ---------------- transpose + convert: in [K][N] f32 -> out [N][K=4096] bf16 ----------------
__global__ void transpose_convert(const float* __restrict__ in,
                                  unsigned short* __restrict__ out, int N) {
  __shared__ float tile[32][33];
  int tx = threadIdx.x, ty = threadIdx.y;       // 32 x 8
  int n0 = blockIdx.x * 32, k0 = blockIdx.y * 32;
#pragma unroll
  for (int i = 0; i < 32; i += 8)
    tile[ty + i][tx] = in[(size_t)(k0 + ty + i) * N + n0 + tx];
  __syncthreads();
#pragma unroll
  for (int i = 0; i < 32; i += 8)
    out[(size_t)(n0 + ty + i) * HID + k0 + tx] = f2bf(tile[tx][ty + i]);
}

// ---------------- bf16 GEMM (m97 structure): C = A[M][K] * Bt[N][K]^T ----------------
// 128x128 tile, BK=32, 256 threads (4 waves 2x2, wave tile 64x64).
// LINEAR LDS [row][32], global_load_lds w=16, double-buffered, 1 barrier/K-step.
__device__ __forceinline__ void storeC(unsigned short* C, size_t idx, float v) { C[idx] = f2bf(v); }
__device__ __forceinline__ void storeC(float* C, size_t idx, float v) { C[idx] = v; }

template <typename OutT>
__launch_bounds__(256, 2)
__global__ void gemm_bt(const unsigned short* __restrict__ A,
                        const unsigned short* __restrict__ Bt,
                        OutT* __restrict__ C, int K, int ldc) {
  __shared__ unsigned short As[2][128 * 32];
  __shared__ unsigned short Bs[2][128 * 32];
  const int tid = threadIdx.x, lane = tid & 63, w = tid >> 6;
  const int wr = w >> 1, wc = w & 1;
  const int m0 = blockIdx.y * 128, n0 = blockIdx.x * 128;
  const int lq = lane & 15, g = lane >> 4;

  f32x4 acc[4][4] = {};

  auto STAGE = [&](int b, int kt) {
#pragma unroll
    for (int i = 0; i < 2; ++i) {
      int row = w * 32 + i * 16 + (lane >> 2);
      int ch = (lane & 3) * 8;
      GLOAD16(A + (size_t)(m0 + row) * K + kt + ch, &As[b][(w * 2 + i) * 512]);
      GLOAD16(Bt + (size_t)(n0 + row) * K + kt + ch, &Bs[b][(w * 2 + i) * 512]);
    }
  };

  STAGE(0, 0);
  __syncthreads();
  int cur = 0;
  for (int kt = 0; kt < K; kt += 32) {
    if (kt + 32 < K) STAGE(cur ^ 1, kt + 32);
    bf16x8 af[4], bfr[4];
#pragma unroll
    for (int mi = 0; mi < 4; ++mi)
      af[mi] = *(const bf16x8*)&As[cur][(wr * 64 + mi * 16 + lq) * 32 + g * 8];
#pragma unroll
    for (int ni = 0; ni < 4; ++ni)
      bfr[ni] = *(const bf16x8*)&Bs[cur][(wc * 64 + ni * 16 + lq) * 32 + g * 8];
#pragma unroll
    for (int mi = 0; mi < 4; ++mi)
#pragma unroll
      for (int ni = 0; ni < 4; ++ni)
        acc[mi][ni] = __builtin_amdgcn_mfma_f32_16x16x32_bf16(af[mi], bfr[ni], acc[mi][ni], 0, 0, 0);
    __syncthreads();
    cur ^= 1;
  }

#pragma unroll
  for (int mi = 0; mi < 4; ++mi) {
#pragma unroll
    for (int ni = 0; ni < 4; ++ni) {
      int row = m0 + wr * 64 + mi * 16 + g * 4;
      int col = n0 + wc * 64 + ni * 16 + lq;
#pragma unroll
      for (int r = 0; r < 4; ++r)
        storeC(C, (size_t)(row + r) * ldc + col, acc[mi][ni][r]);
    }
  }
}

// ---------------- RoPE (in-place on QKV buffer), scale folded into Q ----------------
__global__ void rope_kernel(unsigned short* __restrict__ qkv) {
  int idx = blockIdx.x * blockDim.x + threadIdx.x;  // S * 40 heads * 64 pairs
  int d = idx & 63;
  int h = (idx >> 6) % (NH + NKV);
  int s = (idx >> 6) / (NH + NKV);
  size_t base = (size_t)s * QKVN + (h < NH ? h * HD : NH * HD + (h - NH) * HD);
  float invf = __expf(-(float)d * (1.0f / 64.0f) * 9.210340371976184f);  // 10000^(-d/64)
  float ang = (float)s * invf;
  float c, sn;
  __sincosf(ang, &sn, &c);
  float x1 = bf2f(qkv[base + d]);
  float x2 = bf2f(qkv[base + d + 64]);
  float o1 = x1 * c - x2 * sn;
  float o2 = x2 * c + x1 * sn;
  if (h < NH) {  // fold 1/sqrt(128) attention scale into Q
    o1 *= 0.08838834764831845f;
    o2 *= 0.08838834764831845f;
  }
  qkv[base + d] = f2bf(o1);
  qkv[base + d + 64] = f2bf(o2);
}

// ---------------- flash attention v3 ----------------
// grid (qblk [reversed], head), 256 threads = 4 waves, wave = 16 q-rows. KVBLK=64.
// K: double-buffered [2][64][128] via global_load_lds; source-side inverse XOR swizzle
//    phys_chunk = log_chunk ^ (kv&7); read at chunk (ks*4+g)^(lq&7)  -> conflict-free.
// V: reg-staged transposed Vt[d][kv], stride 88, packed u16x4 (4 kv) writes; kv-chunk
//    even-XOR swizzle: phys4 = (kv>>2) ^ (((d>>3)&3)<<1)  (address-only, reads contiguous).
// P: per-wave Ps[16][88], scalar bf16 writes (round-1-proven pattern).
// T14: K(t+1)/V(t+1) loads issued after barrier B, drained (hidden) at barrier A(t+1).
__launch_bounds__(256, 2)
__global__ void attn_kernel(const unsigned short* __restrict__ qkv,
                            unsigned short* __restrict__ ao) {
  __shared__ unsigned short Ks[2][64 * 128];   // 32 KB
  __shared__ unsigned short Vt[128 * 88];      // 22 KB
  __shared__ unsigned short Ps[4][16 * 88];    // 11 KB

  const int tid = threadIdx.x, lane = tid & 63, w = tid >> 6;
  const int qblk = (int)gridDim.x - 1 - (int)blockIdx.x;  // heavy blocks first
  const int h = blockIdx.y;
  const int kh = h >> 2;  // GQA group of 4
  const int lq = lane & 15, g = lane >> 4;
  const int qbase = qblk * 64 + w * 16;
  const size_t koff = (size_t)NH * HD + (size_t)kh * HD;
  const size_t voff = (size_t)(NH + NKV) * HD + (size_t)kh * HD;

  // Q fragments: qf[ks] = Q[qbase+lq][ks*32 + g*8 ..+8]
  bf16x8 qf[4];
  {
    const unsigned short* qp = qkv + (size_t)(qbase + lq) * QKVN + (size_t)h * HD + g * 8;
#pragma unroll
    for (int ks = 0; ks < 4; ++ks) qf[ks] = *(const bf16x8*)(qp + ks * 32);
  }

  f32x4 o[8] = {};
  float m[4] = {-1e30f, -1e30f, -1e30f, -1e30f};
  float l[4] = {0.f, 0.f, 0.f, 0.f};

  // ---- staging geometry ----
  // K: inst (w,i): rows kvk = (w*4+i)*4 + (lane>>4), phys chunk = lane&15
  auto KSTAGE = [&](int b, int kv0) {
#pragma unroll
    for (int i = 0; i < 4; ++i) {
      int kvk = (w * 4 + i) * 4 + (lane >> 4);
      int chl = (lane & 15) ^ (kvk & 7);
      GLOAD16(qkv + (size_t)(kv0 + kvk) * QKVN + koff + chl * 8, &Ks[b][(w * 4 + i) * 512]);
    }
  };
  // V: thread covers d = vd0..vd0+7 of kv rows vkv..vkv+3
  const int vd0 = (tid & 15) * 8;
  const int vkv = (tid >> 4) * 4;
  u16x8 vr[4];
  auto VLOAD = [&](int kv0) {
#pragma unroll
    for (int i = 0; i < 4; ++i)
      vr[i] = *(const u16x8*)(qkv + (size_t)(kv0 + vkv + i) * QKVN + voff + vd0);
  };
  const int vswz = ((vd0 >> 3) & 3) << 1;              // = (lq&3)<<1 for writers
  const int vcol = (((vkv >> 2) ^ vswz) << 2);
  auto VWRITE = [&]() {
#pragma unroll
    for (int j = 0; j < 8; ++j) {
      u16x4 val = {vr[0][j], vr[1][j], vr[2][j], vr[3][j]};
      *(u16x4*)&Vt[(vd0 + j) * 88 + vcol] = val;
    }
  };

  unsigned short* Pw = &Ps[w][0];
  const int nt = qblk + 1;

  KSTAGE(0, 0);
  VLOAD(0);
  int cur = 0;
  for (int t = 0; t < nt; ++t) {
    const int kv0 = t * 64;
    __syncthreads();                    // A: prev reads done; K(t)/V(t) vmem drained here
    VWRITE();
    __syncthreads();                    // B: Vt visible
    if (t + 1 < nt) { KSTAGE(cur ^ 1, kv0 + 64); VLOAD(kv0 + 64); }  // hidden under compute

    const int nraw = qbase + 16 - kv0;            // >= 16 within nt
    const int nact = nraw > 64 ? 64 : nraw;

    // ---- QK^T ----
    f32x4 sc[4];
#pragma unroll
    for (int st = 0; st < 4; ++st) {
      if (st * 16 < nact) {
        f32x4 s = {};
#pragma unroll
        for (int ks = 0; ks < 4; ++ks) {
          const bf16x8 kf = *(const bf16x8*)
              &Ks[cur][(st * 16 + lq) * 128 + (((ks * 4 + g) ^ (lq & 7)) << 3)];
          s = __builtin_amdgcn_mfma_f32_16x16x32_bf16(qf[ks], kf, s, 0, 0, 0);
        }
        sc[st] = s;
      } else {
        sc[st] = (f32x4){-1e30f, -1e30f, -1e30f, -1e30f};
      }
    }
    if (nraw < 79) {  // diagonal tile: causal mask
#pragma unroll
      for (int st = 0; st < 4; ++st) {
        int col = kv0 + st * 16 + lq;
        int q0 = qbase + g * 4;
#pragma unroll
        for (int r = 0; r < 4; ++r)
          if (col > q0 + r) sc[st][r] = -1e30f;
      }
    }

    // ---- online softmax (16-lane groups: row q = g*4+r, cols = lq across st) ----
    float mn[4], rs[4], alpha[4];
#pragma unroll
    for (int r = 0; r < 4; ++r)
      mn[r] = fmaxf(fmaxf(sc[0][r], sc[1][r]), fmaxf(sc[2][r], sc[3][r]));
#pragma unroll
    for (int off = 1; off < 16; off <<= 1)
#pragma unroll
      for (int r = 0; r < 4; ++r) mn[r] = fmaxf(mn[r], __shfl_xor(mn[r], off, 64));
#pragma unroll
    for (int r = 0; r < 4; ++r) {
      float m2 = fmaxf(m[r], mn[r]);
      alpha[r] = __expf(m[r] - m2);
      m[r] = m2;
      float a = 0.f;
#pragma unroll
      for (int st = 0; st < 4; ++st) {
        float p = __expf(sc[st][r] - m2);
        sc[st][r] = p;
        a += p;
      }
      rs[r] = a;
    }
#pragma unroll
    for (int off = 1; off < 16; off <<= 1)
#pragma unroll
      for (int r = 0; r < 4; ++r) rs[r] += __shfl_xor(rs[r], off, 64);
#pragma unroll
    for (int r = 0; r < 4; ++r) l[r] = l[r] * alpha[r] + rs[r];
#pragma unroll
    for (int p = 0; p < 8; ++p)
#pragma unroll
      for (int r = 0; r < 4; ++r) o[p][r] *= alpha[r];

    // ---- P -> LDS (inactive subtiles hold exp(-1e30-m2)=0) ----
#pragma unroll
    for (int st = 0; st < 4; ++st)
#pragma unroll
      for (int r = 0; r < 4; ++r)
        Pw[(g * 4 + r) * 88 + st * 16 + lq] = f2bf(sc[st][r]);

    // ---- O += P V ----
    const int nks = (nact + 31) >> 5;
    for (int ks = 0; ks < nks; ++ks) {
      const bf16x8 pf = *(const bf16x8*)&Pw[lq * 88 + ks * 32 + g * 8];
#pragma unroll
      for (int p = 0; p < 8; ++p) {
        const int d = p * 16 + lq;
        const int rswz = ((d >> 3) & 3) << 1;
        const int kvc = (ks * 8 + g * 2) ^ rswz;
        const bf16x8 vf = *(const bf16x8*)&Vt[d * 88 + (kvc << 2)];
        o[p] = __builtin_amdgcn_mfma_f32_16x16x32_bf16(pf, vf, o[p], 0, 0, 0);
      }
    }

    cur ^= 1;
  }

  // epilogue: O / l -> ao (bf16, [s][NH*HD])
  float inv[4];
#pragma unroll
  for (int r = 0; r < 4; ++r) inv[r] = 1.0f / l[r];
#pragma unroll
  for (int p = 0; p < 8; ++p)
#pragma unroll
    for (int r = 0; r < 4; ++r)
      ao[(size_t)(qbase + g * 4 + r) * (NH * HD) + (size_t)h * HD + p * 16 + lq] =
          f2bf(o[p][r] * inv[r]);
}

extern "C" void kernel_launch(void* const* d_in, const int* in_sizes, int n_in,
                              void* d_out, int out_size, void* d_ws, size_t ws_size,
                              hipStream_t stream) {
  const float* X  = (const float*)d_in[0];
  const float* qw = (const float*)d_in[2];
  const float* kw = (const float*)d_in[3];
  const float* vw = (const float*)d_in[4];
  const float* ow = (const float*)d_in[5];
  float* out = (float*)d_out;

  char* ws = (char*)d_ws;
  // layout: Xb [0,16M) | Wt [16M,64M) | QKV [64M,88M) | AO [88M,104M)
  // OWt reuses [0,32M) after GEMM1 (Xb and Wt-head are dead by then)
  unsigned short* Xb  = (unsigned short*)(ws);
  unsigned short* Wt  = (unsigned short*)(ws + (size_t)(16u << 20));
  unsigned short* QKV = (unsigned short*)(ws + (size_t)(64u << 20));
  unsigned short* AO  = (unsigned short*)(ws + (size_t)(88u << 20));
  unsigned short* OWt = (unsigned short*)(ws);

  dim3 tb(32, 8);

  // 1. X -> bf16
  convert_kernel<<<(S * HID / 4 + 255) / 256, 256, 0, stream>>>(X, Xb, S * HID / 4);
  // 2. weights -> bf16 transposed [N][K], q/k/v packed into Wt rows [0,6144)
  transpose_convert<<<dim3(HID / 32, HID / 32), tb, 0, stream>>>(qw, Wt, HID);
  transpose_convert<<<dim3((NKV * HD) / 32, HID / 32), tb, 0, stream>>>(kw, Wt + (size_t)(NH * HD) * HID, NKV * HD);
  transpose_convert<<<dim3((NKV * HD) / 32, HID / 32), tb, 0, stream>>>(vw, Wt + (size_t)(NH + NKV) * HD * HID, NKV * HD);
  // 3. QKV = Xb @ Wt^T  (one fused GEMM, N=6144)
  gemm_bt<unsigned short><<<dim3(QKVN / 128, S / 128), 256, 0, stream>>>(Xb, Wt, QKV, HID, QKVN);
  // 4. o_w -> bf16 transposed (into reused region; after GEMM1 in stream order)
  transpose_convert<<<dim3(HID / 32, HID / 32), tb, 0, stream>>>(ow, OWt, HID);
  // 5. RoPE on Q and K (in place), attention scale folded into Q
  rope_kernel<<<(S * (NH + NKV) * 64) / 256, 256, 0, stream>>>(QKV);
  // 6. flash attention
  attn_kernel<<<dim3(S / 64, NH), 256, 0, stream>>>(QKV, AO);
  // 7. out = AO @ OWt^T (fp32 output)
  gemm_bt<float><<<dim3(HID / 128, S / 128), 256, 0, stream>>>(AO, OWt, out, HID, HID);
}